// Round 1
// baseline (345.133 us; speedup 1.0000x reference)
//
#include <hip/hip_runtime.h>
#include <hip/hip_bf16.h>
#include <stdint.h>

#define DIMM 1024
#define HEADS 16
#define HD 64
#define BB 2
#define SS 2048
#define NTOK (BB*SS)

typedef __attribute__((ext_vector_type(8))) __bf16 bf16x8;
typedef __attribute__((ext_vector_type(4))) __bf16 bf16x4;
typedef __attribute__((ext_vector_type(4))) float f32x4;

__device__ __forceinline__ f32x4 mfma16(bf16x8 a, bf16x8 b, f32x4 c) {
  return __builtin_amdgcn_mfma_f32_16x16x32_bf16(a, b, c, 0, 0, 0);
}

__device__ __forceinline__ void gload_lds16(const void* g, void* l) {
  __builtin_amdgcn_global_load_lds(
      (__attribute__((address_space(1))) void*)(void*)g,
      (__attribute__((address_space(3))) void*)l,
      16, 0, 0);
}

// ---------------- convert fp32 -> bf16 ----------------
struct CvtArgs {
  const float* src[7];
  __bf16* dst[7];
  int n[7];
};

__global__ __launch_bounds__(256) void cvt_kernel(CvtArgs a) {
  const int t = blockIdx.y;
  const long i = ((long)blockIdx.x * 256 + threadIdx.x) * 8;
  if (i >= a.n[t]) return;
  const float* s = a.src[t] + i;
  f32x4 x0 = *(const f32x4*)s;
  f32x4 x1 = *(const f32x4*)(s + 4);
  bf16x8 o;
  o[0] = (__bf16)x0[0]; o[1] = (__bf16)x0[1]; o[2] = (__bf16)x0[2]; o[3] = (__bf16)x0[3];
  o[4] = (__bf16)x1[0]; o[5] = (__bf16)x1[1]; o[6] = (__bf16)x1[2]; o[7] = (__bf16)x1[3];
  *(bf16x8*)(a.dst[t] + i) = o;
}

// ---------------- GEMM: C[m,n] = sum_k A[m,k]*B[n,k] + bias[n] ----------------
// M=4096, N=1024, K=1024 hard-coded. BM=64, BN=128, BK=64, 4 waves (2x2).
// MODE 0: bf16 out, head-split [bh][s][64]   (Q,K projections)
// MODE 1: bf16 out, transposed [bh][d][s]    (V projection)
// MODE 2: fp32 out, plain [m][n]             (output projection)
template<int MODE>
__global__ __launch_bounds__(256) void gemm_bt(const __bf16* __restrict__ A,
    const __bf16* __restrict__ Bm, const float* __restrict__ bias,
    void* __restrict__ Cout)
{
  __shared__ __align__(16) char sA[8192];
  __shared__ __align__(16) char sB[16384];
  const int tid = threadIdx.x;
  const int w = tid >> 6, l = tid & 63;
  const int wr = w >> 1, wc = w & 1;
  const int lg = l >> 4, lr = l & 15;
  const int m0 = blockIdx.y * 64, n0 = blockIdx.x * 128;

  f32x4 acc[2][4] = {};

  for (int k0 = 0; k0 < 1024; k0 += 64) {
#pragma unroll
    for (int i = 0; i < 2; ++i) {
      int c = (i * 4 + w) * 64 + l;
      gload_lds16(A + (size_t)(m0 + (c >> 3)) * 1024 + k0 + (c & 7) * 8,
                  sA + (i * 4 + w) * 1024);
    }
#pragma unroll
    for (int i = 0; i < 4; ++i) {
      int c = (i * 4 + w) * 64 + l;
      gload_lds16(Bm + (size_t)(n0 + (c >> 3)) * 1024 + k0 + (c & 7) * 8,
                  sB + (i * 4 + w) * 1024);
    }
    __syncthreads();
#pragma unroll
    for (int kk = 0; kk < 2; ++kk) {
      bf16x8 af[2], bfv[4];
#pragma unroll
      for (int fm = 0; fm < 2; ++fm)
        af[fm] = *(const bf16x8*)(sA + (wr * 32 + fm * 16 + lr) * 128 + kk * 64 + lg * 16);
#pragma unroll
      for (int fn = 0; fn < 4; ++fn)
        bfv[fn] = *(const bf16x8*)(sB + (wc * 64 + fn * 16 + lr) * 128 + kk * 64 + lg * 16);
#pragma unroll
      for (int fm = 0; fm < 2; ++fm)
#pragma unroll
        for (int fn = 0; fn < 4; ++fn)
          acc[fm][fn] = mfma16(af[fm], bfv[fn], acc[fm][fn]);
    }
    __syncthreads();
  }

#pragma unroll
  for (int fm = 0; fm < 2; ++fm) {
#pragma unroll
    for (int fn = 0; fn < 4; ++fn) {
      const int n = n0 + wc * 64 + fn * 16 + lr;
      const int mb = m0 + wr * 32 + fm * 16 + 4 * lg;
      const float bval = bias[n];
      f32x4 vv = acc[fm][fn];
      if constexpr (MODE == 2) {
        float* C = (float*)Cout;
#pragma unroll
        for (int r = 0; r < 4; ++r)
          C[(size_t)(mb + r) * 1024 + n] = vv[r] + bval;
      } else if constexpr (MODE == 0) {
        __bf16* C = (__bf16*)Cout;
        const int hh = n >> 6, d = n & 63;
#pragma unroll
        for (int r = 0; r < 4; ++r) {
          int m = mb + r;
          C[(((size_t)(m >> 11) * 16 + hh) * 2048 + (m & 2047)) * 64 + d] =
              (__bf16)(vv[r] + bval);
        }
      } else {
        __bf16* C = (__bf16*)Cout;
        const int hh = n >> 6, d = n & 63;
        bf16x4 pk;
#pragma unroll
        for (int r = 0; r < 4; ++r) pk[r] = (__bf16)(vv[r] + bval);
        *(bf16x4*)(C + (((size_t)(mb >> 11) * 16 + hh) * 64 + d) * 2048 + (mb & 2047)) = pk;
      }
    }
  }
}

// ---------------- fused attention ----------------
// grid (32 qtiles, 32 bh), 256 threads = 4 waves, wave w owns q rows [w*16, w*16+16)
__global__ __launch_bounds__(256) void attn_kernel(
    const __bf16* __restrict__ Qh, const __bf16* __restrict__ Kh,
    const __bf16* __restrict__ Vt, const int* __restrict__ maskg,
    float* __restrict__ attnW, __bf16* __restrict__ ctx)
{
  __shared__ __align__(16) char sK[4096];
  __shared__ __align__(16) char sV[4096];
  __shared__ __align__(16) char sP[4096];
  __shared__ __align__(16) int sMask[2048];
  __shared__ __align__(16) float sM[4][16];
  __shared__ __align__(16) float sL[4][16];

  const int tid = threadIdx.x;
  const int w = tid >> 6, l = tid & 63;
  const int lg = l >> 4, lr = l & 15;
  const int bh = blockIdx.y;
  const int b = bh >> 4, h = bh & 15;
  const int q0 = blockIdx.x * 64;

  for (int i = tid; i < SS; i += 256) sMask[i] = maskg[(size_t)b * SS + i];

  const __bf16* qbase = Qh + ((size_t)bh * SS + q0 + w * 16 + lr) * HD;
  bf16x8 qf0 = *(const bf16x8*)(qbase + lg * 8);
  bf16x8 qf1 = *(const bf16x8*)(qbase + 32 + lg * 8);

  const __bf16* Khead = Kh + (size_t)bh * SS * HD;
  const __bf16* Vhead = Vt + (size_t)bh * HD * SS;

  float m_run = -INFINITY, l_run = 0.0f;

  __syncthreads();

  // ---- pass 1: per-row running max / sumexp (swapped operands: D[k][q]) ----
  for (int k0 = 0; k0 < SS; k0 += 32) {
    {
      int c = w * 64 + l;
      int kr = c >> 3;
      int dcs = (c & 7) ^ (kr & 7);
      gload_lds16(Khead + (size_t)(k0 + kr) * HD + dcs * 8, sK + w * 1024);
    }
    __syncthreads();
    bf16x8 kf[2][2];
#pragma unroll
    for (int sub = 0; sub < 2; ++sub) {
      int kr = sub * 16 + lr;
#pragma unroll
      for (int dc = 0; dc < 2; ++dc) {
        int ch = (dc * 4 + lg) ^ (kr & 7);
        kf[sub][dc] = *(const bf16x8*)(sK + kr * 128 + ch * 16);
      }
    }
    f32x4 accT[2] = {};
    accT[0] = mfma16(kf[0][0], qf0, accT[0]);
    accT[0] = mfma16(kf[0][1], qf1, accT[0]);
    accT[1] = mfma16(kf[1][0], qf0, accT[1]);
    accT[1] = mfma16(kf[1][1], qf1, accT[1]);

    int4 mk0 = *(const int4*)&sMask[k0 + 4 * lg];
    int4 mk1 = *(const int4*)&sMask[k0 + 16 + 4 * lg];
    float sv[8];
    sv[0] = mk0.x ? accT[0][0] * 0.125f : -1e9f;
    sv[1] = mk0.y ? accT[0][1] * 0.125f : -1e9f;
    sv[2] = mk0.z ? accT[0][2] * 0.125f : -1e9f;
    sv[3] = mk0.w ? accT[0][3] * 0.125f : -1e9f;
    sv[4] = mk1.x ? accT[1][0] * 0.125f : -1e9f;
    sv[5] = mk1.y ? accT[1][1] * 0.125f : -1e9f;
    sv[6] = mk1.z ? accT[1][2] * 0.125f : -1e9f;
    sv[7] = mk1.w ? accT[1][3] * 0.125f : -1e9f;

    float mt = sv[0];
#pragma unroll
    for (int j = 1; j < 8; ++j) mt = fmaxf(mt, sv[j]);
    mt = fmaxf(mt, __shfl_xor(mt, 16));
    mt = fmaxf(mt, __shfl_xor(mt, 32));
    float m_new = fmaxf(m_run, mt);
    float sum = 0.0f;
#pragma unroll
    for (int j = 0; j < 8; ++j) sum += __expf(sv[j] - m_new);
    sum += __shfl_xor(sum, 16);
    sum += __shfl_xor(sum, 32);
    l_run = l_run * __expf(m_run - m_new) + sum;
    m_run = m_new;
    __syncthreads();
  }

  if (lg == 0) { sM[w][lr] = m_run; sL[w][lr] = l_run; }
  __syncthreads();
  f32x4 mq = *(const f32x4*)&sM[w][4 * lg];
  f32x4 lq = *(const f32x4*)&sL[w][4 * lg];
  f32x4 rlq;
#pragma unroll
  for (int r = 0; r < 4; ++r) rlq[r] = 1.0f / lq[r];

  f32x4 Oa[4] = {};
  float* attnrow = attnW + ((size_t)bh * SS + q0 + w * 16 + 4 * lg) * SS;

  // ---- pass 2: P write + PV ----
  for (int k0 = 0; k0 < SS; k0 += 32) {
    {
      int c = w * 64 + l;
      int kr = c >> 3;
      int dcs = (c & 7) ^ (kr & 7);
      gload_lds16(Khead + (size_t)(k0 + kr) * HD + dcs * 8, sK + w * 1024);
    }
    {
      int c = w * 64 + l;
      int d = c >> 2;
      int kcs = (c & 3) ^ ((d >> 1) & 3);
      gload_lds16(Vhead + (size_t)d * SS + k0 + kcs * 8, sV + w * 1024);
    }
    __syncthreads();
    bf16x8 kf[2][2];
#pragma unroll
    for (int sub = 0; sub < 2; ++sub) {
      int kr = sub * 16 + lr;
#pragma unroll
      for (int dc = 0; dc < 2; ++dc) {
        int ch = (dc * 4 + lg) ^ (kr & 7);
        kf[sub][dc] = *(const bf16x8*)(sK + kr * 128 + ch * 16);
      }
    }
    f32x4 acc2[2] = {};
    acc2[0] = mfma16(qf0, kf[0][0], acc2[0]);
    acc2[0] = mfma16(qf1, kf[0][1], acc2[0]);
    acc2[1] = mfma16(qf0, kf[1][0], acc2[1]);
    acc2[1] = mfma16(qf1, kf[1][1], acc2[1]);

    const int mka = sMask[k0 + lr];
    const int mkb = sMask[k0 + 16 + lr];
#pragma unroll
    for (int t = 0; t < 2; ++t) {
      const int mk = t ? mkb : mka;
#pragma unroll
      for (int r = 0; r < 4; ++r) {
        float sp = mk ? acc2[t][r] * 0.125f : -1e9f;
        float p = __expf(sp - mq[r]) * rlq[r];
        attnrow[(size_t)r * SS + k0 + t * 16 + lr] = p;
        int q = 4 * lg + r;
        int ch = (t * 2 + (lr >> 3)) ^ (q & 3);
        *(__bf16*)(sP + w * 1024 + q * 64 + ch * 16 + (lr & 7) * 2) = (__bf16)p;
      }
    }
    __syncthreads();
    bf16x8 pa = *(const bf16x8*)(sP + w * 1024 + lr * 64 + ((lg ^ (lr & 3)) << 4));
#pragma unroll
    for (int dg = 0; dg < 4; ++dg) {
      int d = dg * 16 + lr;
      bf16x8 vb = *(const bf16x8*)(sV + d * 64 + ((lg ^ ((d >> 1) & 3)) << 4));
      Oa[dg] = mfma16(pa, vb, Oa[dg]);
    }
    __syncthreads();
  }

  // epilogue: context -> [b*s][h*64+d] bf16
#pragma unroll
  for (int dg = 0; dg < 4; ++dg)
#pragma unroll
    for (int r = 0; r < 4; ++r)
      ctx[(size_t)(b * SS + q0 + w * 16 + 4 * lg + r) * DIMM + h * HD + dg * 16 + lr] =
          (__bf16)Oa[dg][r];
}

// ---------------- launch ----------------
extern "C" void kernel_launch(void* const* d_in, const int* in_sizes, int n_in,
                              void* d_out, int out_size, void* d_ws, size_t ws_size,
                              hipStream_t stream)
{
  const float* q   = (const float*)d_in[0];
  const float* k   = (const float*)d_in[1];
  const float* v   = (const float*)d_in[2];
  const int*   msk = (const int*)d_in[3];
  const float* Wq  = (const float*)d_in[4];
  const float* bq  = (const float*)d_in[5];
  const float* Wk  = (const float*)d_in[6];
  const float* bk  = (const float*)d_in[7];
  const float* Wv  = (const float*)d_in[8];
  const float* bv  = (const float*)d_in[9];
  const float* Wo  = (const float*)d_in[10];
  const float* bo  = (const float*)d_in[11];

  char* ws = (char*)d_ws;
  __bf16* xq  = (__bf16*)(ws);
  __bf16* xk  = (__bf16*)(ws + (8u << 20));
  __bf16* xv  = (__bf16*)(ws + (16u << 20));
  __bf16* wqb = (__bf16*)(ws + (24u << 20));
  __bf16* wkb = (__bf16*)(ws + (26u << 20));
  __bf16* wvb = (__bf16*)(ws + (28u << 20));
  __bf16* wob = (__bf16*)(ws + (30u << 20));
  __bf16* Qh  = (__bf16*)(ws + (32u << 20));
  __bf16* Kh  = (__bf16*)(ws + (40u << 20));
  __bf16* Vt  = (__bf16*)(ws + (48u << 20));
  __bf16* ctx = (__bf16*)(ws + (56u << 20));

  CvtArgs ca;
  ca.src[0] = q;  ca.dst[0] = xq;  ca.n[0] = NTOK * DIMM;
  ca.src[1] = k;  ca.dst[1] = xk;  ca.n[1] = NTOK * DIMM;
  ca.src[2] = v;  ca.dst[2] = xv;  ca.n[2] = NTOK * DIMM;
  ca.src[3] = Wq; ca.dst[3] = wqb; ca.n[3] = DIMM * DIMM;
  ca.src[4] = Wk; ca.dst[4] = wkb; ca.n[4] = DIMM * DIMM;
  ca.src[5] = Wv; ca.dst[5] = wvb; ca.n[5] = DIMM * DIMM;
  ca.src[6] = Wo; ca.dst[6] = wob; ca.n[6] = DIMM * DIMM;
  cvt_kernel<<<dim3(2048, 7, 1), 256, 0, stream>>>(ca);

  gemm_bt<0><<<dim3(8, 64, 1), 256, 0, stream>>>(xq, wqb, bq, (void*)Qh);
  gemm_bt<0><<<dim3(8, 64, 1), 256, 0, stream>>>(xk, wkb, bk, (void*)Kh);
  gemm_bt<1><<<dim3(8, 64, 1), 256, 0, stream>>>(xv, wvb, bv, (void*)Vt);

  float* out = (float*)d_out;
  float* attnW = out + (size_t)NTOK * DIMM;
  attn_kernel<<<dim3(32, 32, 1), 256, 0, stream>>>(Qh, Kh, Vt, msk, attnW, ctx);

  gemm_bt<2><<<dim3(8, 64, 1), 256, 0, stream>>>(ctx, wob, bo, (void*)out);
}